// Round 5
// baseline (370.607 us; speedup 1.0000x reference)
//
#include <hip/hip_runtime.h>
#include <math.h>

// Problem constants (fixed by the reference)
#define NSK   16       // skills
#define OBSD  376
#define ACTD  17
#define IND   393      // OBS + ACT
#define HD    256      // hidden width
#define MT    16       // rows (samples) per block tile
#define KC    64       // k-chunk for layer-1 x staging
#define XPAD  20       // padded row len for xs[k][r]: %4==0 (16B-aligned), 2-way banks max
#define NCH   7        // ceil(IND / KC)

// d_ws layout (ints):
//   [0..15]   counts per skill
//   [16..31]  exclusive offsets
//   [32..47]  scatter cursors
//   [48..64]  tile-prefix (17 entries)
//   [80..80+B) permutation: skill-sorted sample indices
#define WS_PERM 80

__device__ __forceinline__ float readlane_f(float v, int lane) {
    return __uint_as_float(__builtin_amdgcn_readlane(__float_as_uint(v), (unsigned)lane));
}

__global__ void hist_k(const int* __restrict__ sk, int* __restrict__ ws, int B) {
    __shared__ int h[NSK];
    if (threadIdx.x < NSK) h[threadIdx.x] = 0;
    __syncthreads();
    int i = blockIdx.x * blockDim.x + threadIdx.x;
    if (i < B) atomicAdd(&h[sk[i]], 1);
    __syncthreads();
    if (threadIdx.x < NSK) atomicAdd(&ws[threadIdx.x], h[threadIdx.x]);
}

// Wave-parallel 16-element prefix (replaces serial 1-thread loop).
__global__ void prefix_k(int* __restrict__ ws) {
    int lane = threadIdx.x;            // single wave of 64
    int c = (lane < NSK) ? ws[lane] : 0;
    int t = (c + MT - 1) / MT;
    int xc = c, xt = t;
    #pragma unroll
    for (int off = 1; off < NSK; off <<= 1) {
        int yc = __shfl_up(xc, off, 64);
        int yt = __shfl_up(xt, off, 64);
        if (lane >= off) { xc += yc; xt += yt; }
    }
    if (lane < NSK) {
        int exc = xc - c;   // exclusive row offset
        int ext = xt - t;   // exclusive tile offset
        ws[16 + lane] = exc;
        ws[32 + lane] = exc;
        ws[48 + lane] = ext;
        if (lane == NSK - 1) ws[48 + NSK] = ext + t;
    }
}

// Per-block aggregated scatter: 16 global atomics/block instead of 256.
__global__ void scatter_k(const int* __restrict__ sk, int* __restrict__ ws, int B) {
    __shared__ int lcnt[NSK];
    __shared__ int base[NSK];
    if (threadIdx.x < NSK) lcnt[threadIdx.x] = 0;
    __syncthreads();
    int i = blockIdx.x * blockDim.x + threadIdx.x;
    int s = 0, posl = 0;
    if (i < B) {
        s = sk[i];
        posl = atomicAdd(&lcnt[s], 1);
    }
    __syncthreads();
    if (threadIdx.x < NSK && lcnt[threadIdx.x] > 0)
        base[threadIdx.x] = atomicAdd(&ws[32 + threadIdx.x], lcnt[threadIdx.x]);
    __syncthreads();
    if (i < B) ws[WS_PERM + base[s] + posl] = i;
}

// Fused 3-layer MLP over one 16-row, single-skill tile.
// 256 threads = 4 waves. Thread tile: 4 rows x 4 cols.
// rg = tid>>6 (wave-uniform) selects 4 rows; cg = tid&63 selects 4 cols.
// Wave-uniform rows let layer-2 fetch h1[r][k] via v_readlane (no LDS h).
// __launch_bounds__(256,8): cap VGPR at 64 -> 8 blocks/CU (32 waves/CU).
__global__ __launch_bounds__(256, 8) void moe_k(
    const float* __restrict__ obs, const float* __restrict__ act,
    const float* __restrict__ W1, const float* __restrict__ b1,
    const float* __restrict__ W2, const float* __restrict__ b2,
    const float* __restrict__ W3, const float* __restrict__ b3,
    const int* __restrict__ ws, float* __restrict__ out)
{
    __shared__ int rid[MT];
    __shared__ __align__(16) float xsA[KC][XPAD];
    __shared__ __align__(16) float xsB[KC][XPAD];
    __shared__ int meta[3];

    const int tid = threadIdx.x;

    // XCD-aware bijective swizzle (uniform across the block)
    int n = gridDim.x, bid = blockIdx.x;
    int q8 = n >> 3, r8 = n & 7;
    int xcd = bid & 7, slot = bid >> 3;
    int lid = (xcd < r8) ? (xcd * (q8 + 1) + slot)
                         : (r8 * (q8 + 1) + (xcd - r8) * q8 + slot);

    // parallel tile lookup: thread s checks skill s's tile range
    if (tid < NSK) {
        int t0 = ws[48 + tid], t1 = ws[48 + tid + 1];
        if (lid >= t0 && lid < t1) {
            int t   = lid - t0;
            int cnt = ws[tid];
            meta[0] = tid;
            meta[1] = ws[16 + tid] + t * MT;
            int nr  = cnt - t * MT;
            meta[2] = nr < MT ? nr : MT;
        }
    } else if (tid == 255) {
        if (lid >= ws[48 + NSK]) meta[0] = -1;   // exclusive with the tid<16 writer
    }
    __syncthreads();
    const int sid = meta[0];
    if (sid < 0) return;
    const int start = meta[1];
    const int nrows = meta[2];

    const int* __restrict__ perm = ws + WS_PERM;
    if (tid < MT) {
        int i = tid < nrows ? tid : nrows - 1;   // clamp: dup rows, writes masked later
        rid[tid] = perm[start + i];
    }
    __syncthreads();

    const int rg = tid >> 6;        // 0..3 (wave id) — wave-uniform
    const int cg = tid & 63;        // 0..63
    const int r0 = rg << 2;         // 4 rows per wave-group
    const int c0 = cg << 2;         // 4 cols
    const int rr_ = tid & 15;       // staging: my row slot
    const int qq  = tid >> 4;       // staging: my k sub-group (0..15)
    const long rowb = (long)rid[rr_];

    const float* __restrict__ W1s = W1 + (size_t)sid * (IND * HD);
    const float* __restrict__ W2s = W2 + (size_t)sid * (HD * HD);

    float acc1[4][4];
    #pragma unroll
    for (int i = 0; i < 4; ++i) {
        #pragma unroll
        for (int j = 0; j < 4; ++j) acc1[i][j] = 0.f;
    }

    // staging registers (T14 async split: load early, LDS-write late)
    float4 xq;         // vector path (chunks 0..4, pure obs region)
    float  xr[4];      // scalar path (chunks 5..6, obs/act boundary + tail)

#define LOADC_VEC(C) {                                                       \
        xq = *(const float4*)(obs + rowb * OBSD + (C) * KC + 4 * qq);        \
    }
#define LOADC_SCL(C) {                                                       \
        _Pragma("unroll")                                                    \
        for (int j = 0; j < 4; ++j) {                                        \
            int g = (C) * KC + qq * 4 + j;                                   \
            float v = 0.f;                                                   \
            if (g < OBSD)      v = obs[rowb * OBSD + g];                     \
            else if (g < IND)  v = act[rowb * ACTD + (g - OBSD)];            \
            xr[j] = v;                                                       \
        }                                                                    \
    }
#define WRITE_VEC(BUF) {                                                     \
        BUF[4*qq+0][rr_] = xq.x; BUF[4*qq+1][rr_] = xq.y;                    \
        BUF[4*qq+2][rr_] = xq.z; BUF[4*qq+3][rr_] = xq.w;                    \
    }
#define WRITE_SCL(BUF) {                                                     \
        _Pragma("unroll")                                                    \
        for (int j = 0; j < 4; ++j) BUF[4*qq+j][rr_] = xr[j];                \
    }
#define COMPUTE(BUF, C, KLIM) {                                              \
        const float* wpc = W1s + c0 + (size_t)(C) * KC * HD;                 \
        _Pragma("unroll 8")                                                  \
        for (int k = 0; k < (KLIM); ++k) {                                   \
            float4 wv = *(const float4*)(wpc + k * HD);                      \
            float4 xv = *(const float4*)&BUF[k][r0];                         \
            float xvv[4];                                                    \
            *(float4*)xvv = xv;                                              \
            _Pragma("unroll")                                                \
            for (int i = 0; i < 4; ++i) {                                    \
                acc1[i][0] = fmaf(xvv[i], wv.x, acc1[i][0]);                 \
                acc1[i][1] = fmaf(xvv[i], wv.y, acc1[i][1]);                 \
                acc1[i][2] = fmaf(xvv[i], wv.z, acc1[i][2]);                 \
                acc1[i][3] = fmaf(xvv[i], wv.w, acc1[i][3]);                 \
            }                                                                \
        }                                                                    \
    }

    // ---------------- layer 1: h1 = relu(x @ W1 + b1) ----------------
    // one barrier per chunk; 2 LDS buffers; next chunk's global loads issued
    // before the barrier so they fly during this chunk's compute.
    LOADC_VEC(0);
    #pragma unroll
    for (int c = 0; c < NCH; ++c) {
        float (*buf)[XPAD] = (c & 1) ? xsB : xsA;
        if (c < 5) { WRITE_VEC(buf); } else { WRITE_SCL(buf); }
        if (c + 1 < NCH) {
            if (c + 1 < 5) { LOADC_VEC(c + 1); } else { LOADC_SCL(c + 1); }
        }
        __syncthreads();
        if (c == 6) { COMPUTE(buf, c, IND - 6 * KC); }
        else        { COMPUTE(buf, c, KC); }
    }

    // bias + relu -> h1 (registers; lane cg holds cols c0..c0+3)
    float h1v[4][4];
    {
        float4 b1v = *(const float4*)(b1 + sid * HD + c0);
        #pragma unroll
        for (int i = 0; i < 4; ++i) {
            h1v[i][0] = fmaxf(acc1[i][0] + b1v.x, 0.f);
            h1v[i][1] = fmaxf(acc1[i][1] + b1v.y, 0.f);
            h1v[i][2] = fmaxf(acc1[i][2] + b1v.z, 0.f);
            h1v[i][3] = fmaxf(acc1[i][3] + b1v.w, 0.f);
        }
    }

    // ---------------- layer 2: h2 = relu(h1 @ W2 + b2) ----------------
    // h1[r][k] lives in lane (k>>2), reg (k&3) of this wave -> v_readlane.
    float acc2[4][4];
    #pragma unroll
    for (int i = 0; i < 4; ++i) {
        #pragma unroll
        for (int j = 0; j < 4; ++j) acc2[i][j] = 0.f;
    }
    {
        const float* __restrict__ w2p = W2s + c0;
        #pragma unroll 2
        for (int kk = 0; kk < HD; kk += 4) {
            const int src = kk >> 2;        // wave-uniform source lane
            #pragma unroll
            for (int u = 0; u < 4; ++u) {
                float4 wv = *(const float4*)(w2p + (kk + u) * HD);
                #pragma unroll
                for (int i = 0; i < 4; ++i) {
                    float hv = readlane_f(h1v[i][u], src);
                    acc2[i][0] = fmaf(hv, wv.x, acc2[i][0]);
                    acc2[i][1] = fmaf(hv, wv.y, acc2[i][1]);
                    acc2[i][2] = fmaf(hv, wv.z, acc2[i][2]);
                    acc2[i][3] = fmaf(hv, wv.w, acc2[i][3]);
                }
            }
        }
    }

    // ---------------- layer 3 + sigmoid + scatter-out ----------------
    {
        float4 b2v = *(const float4*)(b2 + sid * HD + c0);
        float4 w3v = *(const float4*)(W3 + sid * HD + c0);
        float part[4];
        #pragma unroll
        for (int i = 0; i < 4; ++i) {
            float h0 = fmaxf(acc2[i][0] + b2v.x, 0.f);
            float h1_ = fmaxf(acc2[i][1] + b2v.y, 0.f);
            float h2_ = fmaxf(acc2[i][2] + b2v.z, 0.f);
            float h3 = fmaxf(acc2[i][3] + b2v.w, 0.f);
            part[i] = h0 * w3v.x + h1_ * w3v.y + h2_ * w3v.z + h3 * w3v.w;
        }
        #pragma unroll
        for (int i = 0; i < 4; ++i) {
            float p = part[i];
            #pragma unroll
            for (int off = 32; off > 0; off >>= 1)
                p += __shfl_xor(p, off, 64);
            part[i] = p;
        }
        if (cg == 0) {
            const float b3v = b3[sid];
            #pragma unroll
            for (int i = 0; i < 4; ++i) {
                int rr = r0 + i;
                if (rr < nrows) {
                    float logit = part[i] + b3v;
                    out[rid[rr]] = 1.f / (1.f + expf(-logit));
                }
            }
        }
    }
}

extern "C" void kernel_launch(void* const* d_in, const int* in_sizes, int n_in,
                              void* d_out, int out_size, void* d_ws, size_t ws_size,
                              hipStream_t stream)
{
    const float* obs = (const float*)d_in[0];
    const float* act = (const float*)d_in[1];
    const int*   sk  = (const int*)d_in[2];
    const float* W1  = (const float*)d_in[3];
    const float* b1  = (const float*)d_in[4];
    const float* W2  = (const float*)d_in[5];
    const float* b2  = (const float*)d_in[6];
    const float* W3  = (const float*)d_in[7];
    const float* b3  = (const float*)d_in[8];
    float* out = (float*)d_out;
    int B = in_sizes[2];
    int* ws = (int*)d_ws;

    // zero the histogram counters (offsets/cursors/tile-prefix are overwritten)
    hipMemsetAsync(ws, 0, 16 * sizeof(int), stream);

    int nb = (B + 255) / 256;
    hipLaunchKernelGGL(hist_k,    dim3(nb), dim3(256), 0, stream, sk, ws, B);
    hipLaunchKernelGGL(prefix_k,  dim3(1),  dim3(64),  0, stream, ws);
    hipLaunchKernelGGL(scatter_k, dim3(nb), dim3(256), 0, stream, sk, ws, B);

    int ntiles = (B + MT - 1) / MT + NSK - 1;   // worst-case tile count
    hipLaunchKernelGGL(moe_k, dim3(ntiles), dim3(256), 0, stream,
                       obs, act, W1, b1, W2, b2, W3, b3, ws, out);
}

// Round 9
// 206.342 us; speedup vs baseline: 1.7961x; 1.7961x over previous
//
#include <hip/hip_runtime.h>
#include <math.h>

// Problem constants
#define NSK   16
#define OBSD  376
#define ACTD  17
#define IND   393      // OBS + ACT
#define HD    256
#define KPAD  416      // IND padded to 13*32
#define NKC1  13       // K-chunks layer 1
#define NKC2  8        // K-chunks layer 2
#define MTM   64       // rows per block (MFMA path)
#define MT32  32       // rows per block (fallback fp32 path)

// ws int layout: [0..15] counts, [16..31] row offsets, [32..47] cursors,
// [48..64] tile prefix, [80..80+B) perm
#define WS_PERM 80
// ws byte layout for converted weights (fragment-linear bf16 planes)
#define W1H_OFF 262144ul
#define F1      (16*NKC1*16*64)                 // 212992 fragments
#define W1L_OFF (W1H_OFF + (size_t)F1*16)
#define W2H_OFF (W1L_OFF + (size_t)F1*16)
#define F2      (16*NKC2*16*64)                 // 131072 fragments
#define W2L_OFF (W2H_OFF + (size_t)F2*16)
#define WS_NEED (W2L_OFF + (size_t)F2*16)       // ~11.3 MB

typedef __attribute__((ext_vector_type(8))) short bf16x8;
typedef __attribute__((ext_vector_type(4))) float f32x4;

__device__ __forceinline__ unsigned short f2bf(float f) {
    unsigned int u = __float_as_uint(f);
    unsigned int r = (u + 0x7FFFu + ((u >> 16) & 1u)) >> 16;
    return (unsigned short)r;
}
__device__ __forceinline__ float bf2f(unsigned short h) {
    return __uint_as_float(((unsigned int)h) << 16);
}
__device__ __forceinline__ float readlane_f(float v, int lane) {
    return __uint_as_float(__builtin_amdgcn_readlane(__float_as_uint(v), (unsigned)lane));
}

// ================= fused prep: block 0 sorts, blocks 1.. convert W =========
__global__ __launch_bounds__(256) void prep_k(
    const int* __restrict__ sk, int* __restrict__ ws, int B,
    const float* __restrict__ W1, const float* __restrict__ W2,
    unsigned char* __restrict__ wsb)
{
    const int tid = threadIdx.x;
    if (blockIdx.x == 0) {
        // ---- single-block histogram + prefix + scatter ----
        __shared__ int h16[NSK];
        __shared__ int cur[NSK];
        if (tid < NSK) h16[tid] = 0;
        __syncthreads();
        const int iters = B / 256;
        for (int i = 0; i < iters; ++i)
            atomicAdd(&h16[sk[i * 256 + tid]], 1);
        __syncthreads();
        if (tid == 0) {
            int acc = 0, tacc = 0;
            for (int s = 0; s < NSK; ++s) {
                int c = h16[s];
                ws[s] = c;
                ws[16 + s] = acc;
                ws[48 + s] = tacc;
                cur[s] = acc;
                acc += c;
                tacc += (c + MTM - 1) / MTM;
            }
            ws[48 + NSK] = tacc;
        }
        __syncthreads();
        for (int i = 0; i < iters; ++i) {
            int idx = i * 256 + tid;
            int s = sk[idx];
            int pos = atomicAdd(&cur[s], 1);
            ws[WS_PERM + pos] = idx;
        }
    } else {
        int wid = blockIdx.x - 1;
        if (wid < F1 / 256) {
            // W1 conversion: frag t = ((s*13+kc)*16+nf)*64+lane
            int t = wid * 256 + tid;
            int s = t / (NKC1 * 16 * 64);
            int rem = t - s * (NKC1 * 16 * 64);
            int kc = rem >> 10;            // /1024
            int nf = (rem >> 6) & 15;
            int lane = rem & 63;
            int k0 = kc * 32 + (lane >> 4) * 8;
            int n = nf * 16 + (lane & 15);
            unsigned short hh[8], ll[8];
            #pragma unroll
            for (int j = 0; j < 8; ++j) {
                int k = k0 + j;
                float v = (k < IND) ? W1[((size_t)s * IND + k) * HD + n] : 0.f;
                unsigned short hi = f2bf(v);
                hh[j] = hi;
                ll[j] = f2bf(v - bf2f(hi));
            }
            uint4 H, L;
            H.x = hh[0] | (hh[1] << 16); H.y = hh[2] | (hh[3] << 16);
            H.z = hh[4] | (hh[5] << 16); H.w = hh[6] | (hh[7] << 16);
            L.x = ll[0] | (ll[1] << 16); L.y = ll[2] | (ll[3] << 16);
            L.z = ll[4] | (ll[5] << 16); L.w = ll[6] | (ll[7] << 16);
            ((uint4*)(wsb + W1H_OFF))[t] = H;
            ((uint4*)(wsb + W1L_OFF))[t] = L;
        } else {
            // W2 conversion: frag t2 = ((s*8+kc2)*16+nf)*64+lane
            int t2 = (wid - F1 / 256) * 256 + tid;
            int s = t2 >> 13;              // /8192
            int kc2 = (t2 >> 10) & 7;
            int nf = (t2 >> 6) & 15;
            int lane = t2 & 63;
            int k0 = kc2 * 32 + (lane >> 4) * 8;
            int n = nf * 16 + (lane & 15);
            unsigned short hh[8], ll[8];
            #pragma unroll
            for (int j = 0; j < 8; ++j) {
                float v = W2[((size_t)s * HD + k0 + j) * HD + n];
                unsigned short hi = f2bf(v);
                hh[j] = hi;
                ll[j] = f2bf(v - bf2f(hi));
            }
            uint4 H, L;
            H.x = hh[0] | (hh[1] << 16); H.y = hh[2] | (hh[3] << 16);
            H.z = hh[4] | (hh[5] << 16); H.w = hh[6] | (hh[7] << 16);
            L.x = ll[0] | (ll[1] << 16); L.y = ll[2] | (ll[3] << 16);
            L.z = ll[4] | (ll[5] << 16); L.w = ll[6] | (ll[7] << 16);
            ((uint4*)(wsb + W2H_OFF))[t2] = H;
            ((uint4*)(wsb + W2L_OFF))[t2] = L;
        }
    }
}

// ================= MFMA fused 3-layer MLP, 64-row single-skill tile ========
// 4 waves split the N dimension (wave w owns cols 64w..64w+64) so W fragments
// are read exactly once per block. bf16 hi/lo split: 3 MFMAs per product.
__global__ __launch_bounds__(256, 2) void moe_m(
    const float* __restrict__ obs, const float* __restrict__ act,
    const float* __restrict__ b1, const float* __restrict__ b2,
    const float* __restrict__ W3, const float* __restrict__ b3,
    const int* __restrict__ ws, const unsigned char* __restrict__ wsb,
    float* __restrict__ out)
{
    __shared__ int rid[MTM];
    __shared__ int meta[3];
    __shared__ float hpart[4][MTM];
    // union region: x staging (hi[2][2048] | lo[2][2048] = hw 0..8192)
    //               h planes   (hhi hw 0..16384, hlo 16384..32768)
    __shared__ __align__(16) unsigned short sm[32768];

    const int tid = threadIdx.x;

    // XCD-aware bijective swizzle
    int n = gridDim.x, bid = blockIdx.x;
    int q8 = n >> 3, r8 = n & 7;
    int xcd = bid & 7, slot = bid >> 3;
    int lid = (xcd < r8) ? (xcd * (q8 + 1) + slot)
                         : (r8 * (q8 + 1) + (xcd - r8) * q8 + slot);

    if (tid < NSK) {
        int t0 = ws[48 + tid], t1 = ws[48 + tid + 1];
        if (lid >= t0 && lid < t1) {
            int t = lid - t0;
            int cnt = ws[tid];
            meta[0] = tid;
            meta[1] = ws[16 + tid] + t * MTM;
            int nr = cnt - t * MTM;
            meta[2] = nr < MTM ? nr : MTM;
        }
    } else if (tid == 255) {
        if (lid >= ws[48 + NSK]) meta[0] = -1;
    }
    __syncthreads();
    const int sid = meta[0];
    if (sid < 0) return;
    const int start = meta[1];
    const int nrows = meta[2];

    if (tid < MTM) {
        int i = tid < nrows ? tid : nrows - 1;
        rid[tid] = ws[WS_PERM + start + i];
    }
    __syncthreads();

    const int w  = tid >> 6;     // wave id: owns cols [64w, 64w+64)
    const int ln = tid & 63;
    const int row_s = tid & 63;  // staging row
    const int kg_s  = tid >> 6;  // staging k-group
    const size_t rowb = (size_t)rid[row_s];

    const uint4* __restrict__ w1h = (const uint4*)(wsb + W1H_OFF);
    const uint4* __restrict__ w1l = (const uint4*)(wsb + W1L_OFF);
    const uint4* __restrict__ w2h = (const uint4*)(wsb + W2H_OFF);
    const uint4* __restrict__ w2l = (const uint4*)(wsb + W2L_OFF);

    float xv[8];

#define LOADX(KC)                                                            \
    if ((KC) < 11) {                                                         \
        const float* p = obs + rowb * OBSD + (KC) * 32 + kg_s * 8;           \
        float4 a_ = *(const float4*)p;                                       \
        float4 b_ = *(const float4*)(p + 4);                                 \
        xv[0]=a_.x; xv[1]=a_.y; xv[2]=a_.z; xv[3]=a_.w;                      \
        xv[4]=b_.x; xv[5]=b_.y; xv[6]=b_.z; xv[7]=b_.w;                      \
    } else {                                                                 \
        _Pragma("unroll")                                                    \
        for (int j = 0; j < 8; ++j) {                                        \
            int k = (KC) * 32 + kg_s * 8 + j;                                \
            float v = 0.f;                                                   \
            if (k < OBSD)     v = obs[rowb * OBSD + k];                      \
            else if (k < IND) v = act[rowb * ACTD + (k - OBSD)];             \
            xv[j] = v;                                                       \
        }                                                                    \
    }

#define WRX(BUF) {                                                           \
        unsigned short hh[8], ll[8];                                         \
        _Pragma("unroll")                                                    \
        for (int j = 0; j < 8; ++j) {                                        \
            unsigned short hi = f2bf(xv[j]);                                 \
            hh[j] = hi; ll[j] = f2bf(xv[j] - bf2f(hi));                      \
        }                                                                    \
        uint4 H, L;                                                          \
        H.x = hh[0]|(hh[1]<<16); H.y = hh[2]|(hh[3]<<16);                    \
        H.z = hh[4]|(hh[5]<<16); H.w = hh[6]|(hh[7]<<16);                    \
        L.x = ll[0]|(ll[1]<<16); L.y = ll[2]|(ll[3]<<16);                    \
        L.z = ll[4]|(ll[5]<<16); L.w = ll[6]|(ll[7]<<16);                    \
        int hw = (BUF) * 2048 + ((row_s >> 4) * 4 + kg_s) * 128              \
                 + (row_s & 15) * 8;                                         \
        *(uint4*)&sm[hw] = H;                                                \
        *(uint4*)&sm[4096 + hw] = L;                                         \
    }

    f32x4 acc[4][4];
    #pragma unroll
    for (int mf = 0; mf < 4; ++mf)
        #pragma unroll
        for (int nf = 0; nf < 4; ++nf)
            acc[mf][nf] = (f32x4){0.f, 0.f, 0.f, 0.f};

    // -------- layer 1: 13 K-chunks, double-buffered x, W frags streamed ----
    LOADX(0)
    WRX(0)
    LOADX(1)
    #pragma unroll
    for (int kc = 0; kc < NKC1; ++kc) {
        __syncthreads();
        if (kc < NKC1 - 1) { WRX((kc + 1) & 1) }
        if (kc < NKC1 - 2) { LOADX(kc + 2) }

        bf16x8 ah[4], al[4], bh[4], bl[4];
        #pragma unroll
        for (int mf = 0; mf < 4; ++mf) {
            int hw = (kc & 1) * 2048 + (mf * 4 + (ln >> 4)) * 128 + (ln & 15) * 8;
            ah[mf] = __builtin_bit_cast(bf16x8, *(const uint4*)&sm[hw]);
            al[mf] = __builtin_bit_cast(bf16x8, *(const uint4*)&sm[4096 + hw]);
        }
        #pragma unroll
        for (int nf = 0; nf < 4; ++nf) {
            int f1 = ((sid * NKC1 + kc) * 16 + (w * 4 + nf)) * 64 + ln;
            bh[nf] = __builtin_bit_cast(bf16x8, w1h[f1]);
            bl[nf] = __builtin_bit_cast(bf16x8, w1l[f1]);
        }
        #pragma unroll
        for (int mf = 0; mf < 4; ++mf)
            #pragma unroll
            for (int nf = 0; nf < 4; ++nf) {
                acc[mf][nf] = __builtin_amdgcn_mfma_f32_16x16x32_bf16(ah[mf], bh[nf], acc[mf][nf], 0, 0, 0);
                acc[mf][nf] = __builtin_amdgcn_mfma_f32_16x16x32_bf16(ah[mf], bl[nf], acc[mf][nf], 0, 0, 0);
                acc[mf][nf] = __builtin_amdgcn_mfma_f32_16x16x32_bf16(al[mf], bh[nf], acc[mf][nf], 0, 0, 0);
            }
    }

    // -------- bias+relu, split to bf16 hi/lo, transpose via LDS ------------
    __syncthreads();   // all x reads done; reuse sm for h planes
    {
        float b1v[4];
        #pragma unroll
        for (int nf = 0; nf < 4; ++nf)
            b1v[nf] = b1[sid * HD + w * 64 + nf * 16 + (ln & 15)];
        #pragma unroll
        for (int mf = 0; mf < 4; ++mf)
            #pragma unroll
            for (int nf = 0; nf < 4; ++nf)
                #pragma unroll
                for (int rg = 0; rg < 4; ++rg) {
                    float v = fmaxf(acc[mf][nf][rg] + b1v[nf], 0.f);
                    unsigned short hi = f2bf(v);
                    unsigned short lo = f2bf(v - bf2f(hi));
                    int col = w * 64 + nf * 16 + (ln & 15);
                    int row = mf * 16 + (ln >> 4) * 4 + rg;
                    int hw = ((col >> 5) * 4 + ((col >> 3) & 3)) * 512 + row * 8 + (col & 7);
                    sm[hw] = hi;
                    sm[16384 + hw] = lo;
                }
    }
    __syncthreads();

    // -------- layer 2: 8 K-chunks, h from LDS, W2 frags streamed -----------
    f32x4 acc2[4][4];
    #pragma unroll
    for (int mf = 0; mf < 4; ++mf)
        #pragma unroll
        for (int nf = 0; nf < 4; ++nf)
            acc2[mf][nf] = (f32x4){0.f, 0.f, 0.f, 0.f};

    #pragma unroll
    for (int kc = 0; kc < NKC2; ++kc) {
        bf16x8 ah[4], al[4], bh[4], bl[4];
        #pragma unroll
        for (int mf = 0; mf < 4; ++mf) {
            int hw = (kc * 4 + (ln >> 4)) * 512 + (mf * 16 + (ln & 15)) * 8;
            ah[mf] = __builtin_bit_cast(bf16x8, *(const uint4*)&sm[hw]);
            al[mf] = __builtin_bit_cast(bf16x8, *(const uint4*)&sm[16384 + hw]);
        }
        #pragma unroll
        for (int nf = 0; nf < 4; ++nf) {
            int f2 = ((sid * NKC2 + kc) * 16 + (w * 4 + nf)) * 64 + ln;
            bh[nf] = __builtin_bit_cast(bf16x8, w2h[f2]);
            bl[nf] = __builtin_bit_cast(bf16x8, w2l[f2]);
        }
        #pragma unroll
        for (int mf = 0; mf < 4; ++mf)
            #pragma unroll
            for (int nf = 0; nf < 4; ++nf) {
                acc2[mf][nf] = __builtin_amdgcn_mfma_f32_16x16x32_bf16(ah[mf], bh[nf], acc2[mf][nf], 0, 0, 0);
                acc2[mf][nf] = __builtin_amdgcn_mfma_f32_16x16x32_bf16(ah[mf], bl[nf], acc2[mf][nf], 0, 0, 0);
                acc2[mf][nf] = __builtin_amdgcn_mfma_f32_16x16x32_bf16(al[mf], bh[nf], acc2[mf][nf], 0, 0, 0);
            }
    }

    // -------- layer 3: bias+relu, dot W3, reduce, sigmoid ------------------
    {
        float w3v[4], b2v[4];
        #pragma unroll
        for (int nf = 0; nf < 4; ++nf) {
            int nn = w * 64 + nf * 16 + (ln & 15);
            w3v[nf] = W3[sid * HD + nn];
            b2v[nf] = b2[sid * HD + nn];
        }
        #pragma unroll
        for (int mf = 0; mf < 4; ++mf)
            #pragma unroll
            for (int rg = 0; rg < 4; ++rg) {
                float p = 0.f;
                #pragma unroll
                for (int nf = 0; nf < 4; ++nf)
                    p += fmaxf(acc2[mf][nf][rg] + b2v[nf], 0.f) * w3v[nf];
                p += __shfl_xor(p, 1, 64);
                p += __shfl_xor(p, 2, 64);
                p += __shfl_xor(p, 4, 64);
                p += __shfl_xor(p, 8, 64);
                if ((ln & 15) == 0)
                    hpart[w][mf * 16 + (ln >> 4) * 4 + rg] = p;
            }
    }
    __syncthreads();
    if (tid < MTM) {
        float s = hpart[0][tid] + hpart[1][tid] + hpart[2][tid] + hpart[3][tid] + b3[sid];
        if (tid < nrows)
            out[rid[tid]] = 1.f / (1.f + expf(-s));
    }
}

// ======================= fallback fp32 path (measured 218us) ===============
__global__ void hist_k(const int* __restrict__ sk, int* __restrict__ ws, int B) {
    __shared__ int h[NSK];
    if (threadIdx.x < NSK) h[threadIdx.x] = 0;
    __syncthreads();
    int i = blockIdx.x * blockDim.x + threadIdx.x;
    if (i < B) atomicAdd(&h[sk[i]], 1);
    __syncthreads();
    if (threadIdx.x < NSK) atomicAdd(&ws[threadIdx.x], h[threadIdx.x]);
}

__global__ void prefix_k(int* __restrict__ ws) {
    if (threadIdx.x == 0 && blockIdx.x == 0) {
        int acc = 0, tacc = 0;
        for (int s = 0; s < NSK; ++s) {
            int c = ws[s];
            ws[16 + s] = acc;
            ws[32 + s] = acc;
            ws[48 + s] = tacc;
            acc += c;
            tacc += (c + MT32 - 1) / MT32;
        }
        ws[48 + NSK] = tacc;
    }
}

__global__ void scatter_k(const int* __restrict__ sk, int* __restrict__ ws, int B) {
    __shared__ int lcnt[NSK];
    __shared__ int base[NSK];
    if (threadIdx.x < NSK) lcnt[threadIdx.x] = 0;
    __syncthreads();
    int i = blockIdx.x * blockDim.x + threadIdx.x;
    int s = 0, posl = 0;
    if (i < B) { s = sk[i]; posl = atomicAdd(&lcnt[s], 1); }
    __syncthreads();
    if (threadIdx.x < NSK && lcnt[threadIdx.x] > 0)
        base[threadIdx.x] = atomicAdd(&ws[32 + threadIdx.x], lcnt[threadIdx.x]);
    __syncthreads();
    if (i < B) ws[WS_PERM + base[s] + posl] = i;
}

#define KC32  64
#define XPAD32 36
#define NCH32 7
__global__ __launch_bounds__(256, 4) void moe_k32(
    const float* __restrict__ obs, const float* __restrict__ act,
    const float* __restrict__ W1, const float* __restrict__ b1,
    const float* __restrict__ W2, const float* __restrict__ b2,
    const float* __restrict__ W3, const float* __restrict__ b3,
    const int* __restrict__ ws, float* __restrict__ out)
{
    __shared__ int rid[MT32];
    __shared__ __align__(16) float xsA[KC32][XPAD32];
    __shared__ __align__(16) float xsB[KC32][XPAD32];
    __shared__ int meta[3];
    const int tid = threadIdx.x;
    int n = gridDim.x, bid = blockIdx.x;
    int q8 = n >> 3, r8 = n & 7;
    int xcd = bid & 7, slot = bid >> 3;
    int lid = (xcd < r8) ? (xcd * (q8 + 1) + slot)
                         : (r8 * (q8 + 1) + (xcd - r8) * q8 + slot);
    if (tid < NSK) {
        int t0 = ws[48 + tid], t1 = ws[48 + tid + 1];
        if (lid >= t0 && lid < t1) {
            int t = lid - t0;
            int cnt = ws[tid];
            meta[0] = tid;
            meta[1] = ws[16 + tid] + t * MT32;
            int nr = cnt - t * MT32;
            meta[2] = nr < MT32 ? nr : MT32;
        }
    } else if (tid == 255) {
        if (lid >= ws[48 + NSK]) meta[0] = -1;
    }
    __syncthreads();
    const int sid = meta[0];
    if (sid < 0) return;
    const int start = meta[1];
    const int nrows = meta[2];
    const int* __restrict__ perm = ws + WS_PERM;
    if (tid < MT32) {
        int i = tid < nrows ? tid : nrows - 1;
        rid[tid] = perm[start + i];
    }
    __syncthreads();
    const int rg = tid >> 6, cg = tid & 63;
    const int r0 = rg << 3, c0 = cg << 2;
    const int rr_ = tid & 31, qq = tid >> 5;
    const long rowb = (long)rid[rr_];
    const float* __restrict__ W1s = W1 + (size_t)sid * (IND * HD);
    const float* __restrict__ W2s = W2 + (size_t)sid * (HD * HD);
    float acc1[8][4];
    #pragma unroll
    for (int i = 0; i < 8; ++i)
        #pragma unroll
        for (int j = 0; j < 4; ++j) acc1[i][j] = 0.f;
    float4 xq0, xq1;
    float xr[8];
#define LOADC_VEC(C) {                                                       \
        const float* p = obs + rowb * OBSD + (C) * KC32 + 4 * qq;            \
        xq0 = *(const float4*)(p); xq1 = *(const float4*)(p + 32);           \
    }
#define LOADC_SCL(C) {                                                       \
        _Pragma("unroll")                                                    \
        for (int it = 0; it < 8; ++it) {                                     \
            int g = (C) * KC32 + it * 8 + qq;                                \
            float v = 0.f;                                                   \
            if (g < OBSD)      v = obs[rowb * OBSD + g];                     \
            else if (g < IND)  v = act[rowb * ACTD + (g - OBSD)];            \
            xr[it] = v;                                                      \
        }                                                                    \
    }
#define WRITE_VEC(BUF) {                                                     \
        BUF[4*qq+0][rr_] = xq0.x; BUF[4*qq+1][rr_] = xq0.y;                  \
        BUF[4*qq+2][rr_] = xq0.z; BUF[4*qq+3][rr_] = xq0.w;                  \
        BUF[32+4*qq+0][rr_] = xq1.x; BUF[32+4*qq+1][rr_] = xq1.y;            \
        BUF[32+4*qq+2][rr_] = xq1.z; BUF[32+4*qq+3][rr_] = xq1.w;            \
    }
#define WRITE_SCL(BUF) {                                                     \
        _Pragma("unroll")                                                    \
        for (int it = 0; it < 8; ++it) BUF[it*8+qq][rr_] = xr[it];           \
    }
#define COMPUTE32(BUF, C, KLIM) {                                            \
        const float* wpc = W1s + c0 + (size_t)(C) * KC32 * HD;               \
        _Pragma("unroll 4")                                                  \
        for (int k = 0; k < (KLIM); ++k) {                                   \
            float4 wv = *(const float4*)(wpc + k * HD);                      \
            const float4* xp = (const float4*)&BUF[k][r0];                   \
            float xvv[8];                                                    \
            *(float4*)(xvv + 0) = xp[0];                                     \
            *(float4*)(xvv + 4) = xp[1];                                     \
            _Pragma("unroll")                                                \
            for (int i = 0; i < 8; ++i) {                                    \
                acc1[i][0] = fmaf(xvv[i], wv.x, acc1[i][0]);                 \
                acc1[i][1] = fmaf(xvv[i], wv.y, acc1[i][1]);                 \
                acc1[i][2] = fmaf(xvv[i], wv.z, acc1[i][2]);                 \
                acc1[i][3] = fmaf(xvv[i], wv.w, acc1[i][3]);                 \
            }                                                                \
        }                                                                    \
    }
    LOADC_VEC(0);
    #pragma unroll
    for (int c = 0; c < NCH32; ++c) {
        float (*buf)[XPAD32] = (c & 1) ? xsB : xsA;
        if (c < 5) { WRITE_VEC(buf); } else { WRITE_SCL(buf); }
        if (c + 1 < NCH32) {
            if (c + 1 < 5) { LOADC_VEC(c + 1); } else { LOADC_SCL(c + 1); }
        }
        __syncthreads();
        if (c == 6) { COMPUTE32(buf, c, IND - 6 * KC32); }
        else        { COMPUTE32(buf, c, KC32); }
    }
    float h1v[8][4];
    {
        float4 b1v = *(const float4*)(b1 + sid * HD + c0);
        #pragma unroll
        for (int i = 0; i < 8; ++i) {
            h1v[i][0] = fmaxf(acc1[i][0] + b1v.x, 0.f);
            h1v[i][1] = fmaxf(acc1[i][1] + b1v.y, 0.f);
            h1v[i][2] = fmaxf(acc1[i][2] + b1v.z, 0.f);
            h1v[i][3] = fmaxf(acc1[i][3] + b1v.w, 0.f);
        }
    }
    float acc2[8][4];
    #pragma unroll
    for (int i = 0; i < 8; ++i)
        #pragma unroll
        for (int j = 0; j < 4; ++j) acc2[i][j] = 0.f;
    {
        const float* __restrict__ w2p = W2s + c0;
        float4 wqA[4], wqB[4];
        #pragma unroll
        for (int u = 0; u < 4; ++u) wqA[u] = *(const float4*)(w2p + u * HD);
#define L2_GRP(WQ, SRC) {                                                    \
        _Pragma("unroll")                                                    \
        for (int u = 0; u < 4; ++u) {                                        \
            _Pragma("unroll")                                                \
            for (int i = 0; i < 8; ++i) {                                    \
                float hv = readlane_f(h1v[i][u], (SRC));                     \
                acc2[i][0] = fmaf(hv, WQ[u].x, acc2[i][0]);                  \
                acc2[i][1] = fmaf(hv, WQ[u].y, acc2[i][1]);                  \
                acc2[i][2] = fmaf(hv, WQ[u].z, acc2[i][2]);                  \
                acc2[i][3] = fmaf(hv, WQ[u].w, acc2[i][3]);                  \
            }                                                                \
        }                                                                    \
    }
        for (int kk = 0; kk < HD; kk += 8) {
            #pragma unroll
            for (int u = 0; u < 4; ++u)
                wqB[u] = *(const float4*)(w2p + (kk + 4 + u) * HD);
            L2_GRP(wqA, kk >> 2);
            if (kk + 8 < HD) {
                #pragma unroll
                for (int u = 0; u < 4; ++u)
                    wqA[u] = *(const float4*)(w2p + (kk + 8 + u) * HD);
            }
            L2_GRP(wqB, (kk >> 2) + 1);
        }
#undef L2_GRP
    }
    {
        float4 b2v = *(const float4*)(b2 + sid * HD + c0);
        float4 w3v = *(const float4*)(W3 + sid * HD + c0);
        float part[8];
        #pragma unroll
        for (int i = 0; i < 8; ++i) {
            float h0 = fmaxf(acc2[i][0] + b2v.x, 0.f);
            float h1_ = fmaxf(acc2[i][1] + b2v.y, 0.f);
            float h2_ = fmaxf(acc2[i][2] + b2v.z, 0.f);
            float h3 = fmaxf(acc2[i][3] + b2v.w, 0.f);
            part[i] = h0 * w3v.x + h1_ * w3v.y + h2_ * w3v.z + h3 * w3v.w;
        }
        #pragma unroll
        for (int i = 0; i < 8; ++i) {
            float p = part[i];
            #pragma unroll
            for (int off = 32; off > 0; off >>= 1)
                p += __shfl_xor(p, off, 64);
            part[i] = p;
        }
        if (cg == 0) {
            const float b3v = b3[sid];
            #pragma unroll
            for (int i = 0; i < 8; ++i) {
                int rr = r0 + i;
                if (rr < nrows) {
                    float logit = part[i] + b3v;
                    out[rid[rr]] = 1.f / (1.f + expf(-logit));
                }
            }
        }
    }
}

extern "C" void kernel_launch(void* const* d_in, const int* in_sizes, int n_in,
                              void* d_out, int out_size, void* d_ws, size_t ws_size,
                              hipStream_t stream)
{
    const float* obs = (const float*)d_in[0];
    const float* act = (const float*)d_in[1];
    const int*   sk  = (const int*)d_in[2];
    const float* W1  = (const float*)d_in[3];
    const float* b1  = (const float*)d_in[4];
    const float* W2  = (const float*)d_in[5];
    const float* b2  = (const float*)d_in[6];
    const float* W3  = (const float*)d_in[7];
    const float* b3  = (const float*)d_in[8];
    float* out = (float*)d_out;
    int B = in_sizes[2];
    int* ws = (int*)d_ws;
    unsigned char* wsb = (unsigned char*)d_ws;

    if (ws_size >= WS_NEED) {
        // MFMA path: fused prep (sort + W conversion), then fused MLP
        int prep_blocks = 1 + F1 / 256 + F2 / 256;   // 1 + 832 + 512
        hipLaunchKernelGGL(prep_k, dim3(prep_blocks), dim3(256), 0, stream,
                           sk, ws, B, W1, W2, wsb);
        int ntiles = B / MTM + NSK - 1;              // 527 worst case
        hipLaunchKernelGGL(moe_m, dim3(ntiles), dim3(256), 0, stream,
                           obs, act, b1, b2, W3, b3, ws, wsb, out);
    } else {
        // fallback: measured-good fp32 path
        hipMemsetAsync(ws, 0, 16 * sizeof(int), stream);
        int nb = (B + 255) / 256;
        hipLaunchKernelGGL(hist_k,    dim3(nb), dim3(256), 0, stream, sk, ws, B);
        hipLaunchKernelGGL(prefix_k,  dim3(1),  dim3(64),  0, stream, ws);
        hipLaunchKernelGGL(scatter_k, dim3(nb), dim3(256), 0, stream, sk, ws, B);
        int ntiles = (B + MT32 - 1) / MT32 + NSK - 1;
        hipLaunchKernelGGL(moe_k32, dim3(ntiles), dim3(256), 0, stream,
                           obs, act, W1, b1, W2, b2, W3, b3, ws, out);
    }
}

// Round 10
// 162.046 us; speedup vs baseline: 2.2870x; 1.2734x over previous
//
#include <hip/hip_runtime.h>
#include <math.h>

// Problem constants
#define NSK   16
#define OBSD  376
#define ACTD  17
#define IND   393      // OBS + ACT
#define HD    256
#define NKC1  13       // K-chunks layer 1 (K=32 each, 416 padded)
#define NKC2  8        // K-chunks layer 2
#define MTM   32       // rows per block (MFMA path)

// ws int layout: [0..15] counts, [16..31] row offsets, [32..47] cursors,
// [48..64] tile prefix, [80..80+B) perm
#define WS_PERM 80
// ws byte layout for converted weights (fragment-linear bf16 planes)
#define W1H_OFF 262144ul
#define F1      (16*NKC1*16*64)                 // 212992 fragments
#define W1L_OFF (W1H_OFF + (size_t)F1*16)
#define W2H_OFF (W1L_OFF + (size_t)F1*16)
#define F2      (16*NKC2*16*64)                 // 131072 fragments
#define W2L_OFF (W2H_OFF + (size_t)F2*16)
#define WS_NEED (W2L_OFF + (size_t)F2*16)       // ~11.3 MB

// LDS short-index offsets (union: x staging dies before h is written)
#define XROWP 40            // x row stride in shorts (80B, 16B-aligned, 2-way banks)
#define XPLN  (MTM*XROWP)   // 1280 shorts per plane per buffer
#define XB(buf,pln) ((buf)*2*XPLN + (pln)*XPLN)
#define HROWP 264           // h row stride in shorts (528B, 16B-aligned, 2-way banks)
#define H_HI  0
#define H_LO  (MTM*HROWP)   // 8448
#define SM_TOT (2*MTM*HROWP) // 16896 shorts = 33792 B

typedef __attribute__((ext_vector_type(8))) short bf16x8;
typedef __attribute__((ext_vector_type(4))) float f32x4;

__device__ __forceinline__ unsigned short f2bf(float f) {
    unsigned int u = __float_as_uint(f);
    unsigned int r = (u + 0x7FFFu + ((u >> 16) & 1u)) >> 16;
    return (unsigned short)r;
}
__device__ __forceinline__ float bf2f(unsigned short h) {
    return __uint_as_float(((unsigned int)h) << 16);
}

// ============ fused kernel 1: parallel histogram (blocks 0..NBH-1) =========
// ============                + W conversion     (blocks NBH..)     =========
#define NBH 128   // B/256
__global__ __launch_bounds__(256) void sortconv_k(
    const int* __restrict__ sk, int* __restrict__ ws, int B,
    const float* __restrict__ W1, const float* __restrict__ W2,
    unsigned char* __restrict__ wsb)
{
    const int tid = threadIdx.x;
    if (blockIdx.x < NBH) {
        __shared__ int h16[NSK];
        if (tid < NSK) h16[tid] = 0;
        __syncthreads();
        int i = blockIdx.x * 256 + tid;
        if (i < B) atomicAdd(&h16[sk[i]], 1);
        __syncthreads();
        if (tid < NSK && h16[tid] > 0) atomicAdd(&ws[tid], h16[tid]);
    } else {
        int wid = blockIdx.x - NBH;
        if (wid < F1 / 256) {
            // W1: frag t = ((s*13+kc)*16+nf)*64+lane
            int t = wid * 256 + tid;
            int s = t / (NKC1 * 16 * 64);
            int rem = t - s * (NKC1 * 16 * 64);
            int kc = rem >> 10;
            int nf = (rem >> 6) & 15;
            int lane = rem & 63;
            int k0 = kc * 32 + (lane >> 4) * 8;
            int n = nf * 16 + (lane & 15);
            unsigned short hh[8], ll[8];
            #pragma unroll
            for (int j = 0; j < 8; ++j) {
                int k = k0 + j;
                float v = (k < IND) ? W1[((size_t)s * IND + k) * HD + n] : 0.f;
                unsigned short hi = f2bf(v);
                hh[j] = hi;
                ll[j] = f2bf(v - bf2f(hi));
            }
            uint4 H, L;
            H.x = hh[0] | (hh[1] << 16); H.y = hh[2] | (hh[3] << 16);
            H.z = hh[4] | (hh[5] << 16); H.w = hh[6] | (hh[7] << 16);
            L.x = ll[0] | (ll[1] << 16); L.y = ll[2] | (ll[3] << 16);
            L.z = ll[4] | (ll[5] << 16); L.w = ll[6] | (ll[7] << 16);
            ((uint4*)(wsb + W1H_OFF))[t] = H;
            ((uint4*)(wsb + W1L_OFF))[t] = L;
        } else {
            // W2: frag t2 = ((s*8+kc2)*16+nf)*64+lane
            int t2 = (wid - F1 / 256) * 256 + tid;
            int s = t2 >> 13;
            int kc2 = (t2 >> 10) & 7;
            int nf = (t2 >> 6) & 15;
            int lane = t2 & 63;
            int k0 = kc2 * 32 + (lane >> 4) * 8;
            int n = nf * 16 + (lane & 15);
            unsigned short hh[8], ll[8];
            #pragma unroll
            for (int j = 0; j < 8; ++j) {
                float v = W2[((size_t)s * HD + k0 + j) * HD + n];
                unsigned short hi = f2bf(v);
                hh[j] = hi;
                ll[j] = f2bf(v - bf2f(hi));
            }
            uint4 H, L;
            H.x = hh[0] | (hh[1] << 16); H.y = hh[2] | (hh[3] << 16);
            H.z = hh[4] | (hh[5] << 16); H.w = hh[6] | (hh[7] << 16);
            L.x = ll[0] | (ll[1] << 16); L.y = ll[2] | (ll[3] << 16);
            L.z = ll[4] | (ll[5] << 16); L.w = ll[6] | (ll[7] << 16);
            ((uint4*)(wsb + W2H_OFF))[t2] = H;
            ((uint4*)(wsb + W2L_OFF))[t2] = L;
        }
    }
}

// ===================== wave-parallel 16-entry prefix =======================
__global__ void prefix_k(int* __restrict__ ws) {
    int lane = threadIdx.x;            // one wave of 64
    int c = (lane < NSK) ? ws[lane] : 0;
    int t = (c + MTM - 1) / MTM;
    int xc = c, xt = t;
    #pragma unroll
    for (int off = 1; off < NSK; off <<= 1) {
        int yc = __shfl_up(xc, off, 64);
        int yt = __shfl_up(xt, off, 64);
        if (lane >= off) { xc += yc; xt += yt; }
    }
    if (lane < NSK) {
        int exc = xc - c;
        int ext = xt - t;
        ws[16 + lane] = exc;
        ws[32 + lane] = exc;
        ws[48 + lane] = ext;
        if (lane == NSK - 1) ws[48 + NSK] = ext + t;
    }
}

// ============== aggregated scatter: 16 global atomics per block ============
__global__ void scatter_k(const int* __restrict__ sk, int* __restrict__ ws, int B) {
    __shared__ int lcnt[NSK];
    __shared__ int base[NSK];
    if (threadIdx.x < NSK) lcnt[threadIdx.x] = 0;
    __syncthreads();
    int i = blockIdx.x * blockDim.x + threadIdx.x;
    int s = 0, posl = 0;
    if (i < B) { s = sk[i]; posl = atomicAdd(&lcnt[s], 1); }
    __syncthreads();
    if (threadIdx.x < NSK && lcnt[threadIdx.x] > 0)
        base[threadIdx.x] = atomicAdd(&ws[32 + threadIdx.x], lcnt[threadIdx.x]);
    __syncthreads();
    if (i < B) ws[WS_PERM + base[s] + posl] = i;
}

// ========== MFMA fused 3-layer MLP, 32-row single-skill tile ==============
// 4 waves split N (wave w owns cols 64w..64w+64); W frags read once/block.
// bf16 hi/lo split: 3 MFMAs per product. 4 blocks/CU (LDS ~34 KB, VGPR<=128).
__global__ __launch_bounds__(256, 4) void moe_m(
    const float* __restrict__ obs, const float* __restrict__ act,
    const float* __restrict__ b1, const float* __restrict__ b2,
    const float* __restrict__ W3, const float* __restrict__ b3,
    const int* __restrict__ ws, const unsigned char* __restrict__ wsb,
    float* __restrict__ out)
{
    __shared__ int rid[MTM];
    __shared__ int meta[3];
    __shared__ float hpart[4][MTM];
    __shared__ __align__(16) unsigned short sm[SM_TOT];

    const int tid = threadIdx.x;

    // XCD-aware bijective swizzle
    int n = gridDim.x, bid = blockIdx.x;
    int q8 = n >> 3, r8 = n & 7;
    int xcd = bid & 7, slot = bid >> 3;
    int lid = (xcd < r8) ? (xcd * (q8 + 1) + slot)
                         : (r8 * (q8 + 1) + (xcd - r8) * q8 + slot);

    if (tid < NSK) {
        int t0 = ws[48 + tid], t1 = ws[48 + tid + 1];
        if (lid >= t0 && lid < t1) {
            int t = lid - t0;
            int cnt = ws[tid];
            meta[0] = tid;
            meta[1] = ws[16 + tid] + t * MTM;
            int nr = cnt - t * MTM;
            meta[2] = nr < MTM ? nr : MTM;
        }
    } else if (tid == 255) {
        if (lid >= ws[48 + NSK]) meta[0] = -1;
    }
    __syncthreads();
    const int sid = meta[0];
    if (sid < 0) return;
    const int start = meta[1];
    const int nrows = meta[2];

    if (tid < MTM) {
        int i = tid < nrows ? tid : nrows - 1;
        rid[tid] = ws[WS_PERM + start + i];
    }
    __syncthreads();

    const int w  = tid >> 6;     // wave id: cols [64w, 64w+64)
    const int ln = tid & 63;
    const int row_s = tid & 31;  // staging row
    const int kg_s  = tid >> 5;  // staging k-subgroup (0..7), 4 k each
    const size_t rowb = (size_t)rid[row_s];

    const uint4* __restrict__ w1h = (const uint4*)(wsb + W1H_OFF);
    const uint4* __restrict__ w1l = (const uint4*)(wsb + W1L_OFF);
    const uint4* __restrict__ w2h = (const uint4*)(wsb + W2H_OFF);
    const uint4* __restrict__ w2l = (const uint4*)(wsb + W2L_OFF);

    float xv[4];

#define LOADX(KC)                                                            \
    if ((KC) < 11) {                                                         \
        float4 a_ = *(const float4*)(obs + rowb * OBSD + (KC) * 32 + kg_s * 4);\
        xv[0]=a_.x; xv[1]=a_.y; xv[2]=a_.z; xv[3]=a_.w;                      \
    } else {                                                                 \
        _Pragma("unroll")                                                    \
        for (int j = 0; j < 4; ++j) {                                        \
            int k = (KC) * 32 + kg_s * 4 + j;                                \
            float v = 0.f;                                                   \
            if (k < OBSD)     v = obs[rowb * OBSD + k];                      \
            else if (k < IND) v = act[rowb * ACTD + (k - OBSD)];             \
            xv[j] = v;                                                       \
        }                                                                    \
    }

#define WRX(BUF) {                                                           \
        unsigned short hh[4], ll[4];                                         \
        _Pragma("unroll")                                                    \
        for (int j = 0; j < 4; ++j) {                                        \
            unsigned short hi = f2bf(xv[j]);                                 \
            hh[j] = hi; ll[j] = f2bf(xv[j] - bf2f(hi));                      \
        }                                                                    \
        uint2 H, L;                                                          \
        H.x = hh[0]|(hh[1]<<16); H.y = hh[2]|(hh[3]<<16);                    \
        L.x = ll[0]|(ll[1]<<16); L.y = ll[2]|(ll[3]<<16);                    \
        int o = row_s * XROWP + kg_s * 4;                                    \
        *(uint2*)&sm[XB(BUF,0) + o] = H;                                     \
        *(uint2*)&sm[XB(BUF,1) + o] = L;                                     \
    }

    f32x4 acc[2][4];
    #pragma unroll
    for (int mf = 0; mf < 2; ++mf)
        #pragma unroll
        for (int nf = 0; nf < 4; ++nf)
            acc[mf][nf] = (f32x4){0.f, 0.f, 0.f, 0.f};

    // -------- layer 1: 13 K-chunks, double-buffered x, W frags streamed ----
    LOADX(0)
    WRX(0)
    LOADX(1)
    #pragma unroll
    for (int kc = 0; kc < NKC1; ++kc) {
        __syncthreads();
        if (kc < NKC1 - 1) { WRX((kc + 1) & 1) }
        if (kc < NKC1 - 2) { LOADX(kc + 2) }

        bf16x8 ah[2], al[2], bh[4], bl[4];
        #pragma unroll
        for (int nf = 0; nf < 4; ++nf) {
            int f1 = ((sid * NKC1 + kc) * 16 + (w * 4 + nf)) * 64 + ln;
            bh[nf] = __builtin_bit_cast(bf16x8, w1h[f1]);
            bl[nf] = __builtin_bit_cast(bf16x8, w1l[f1]);
        }
        #pragma unroll
        for (int mf = 0; mf < 2; ++mf) {
            int o = (kc & 1) * 2 * XPLN + (mf * 16 + (ln & 15)) * XROWP + (ln >> 4) * 8;
            ah[mf] = __builtin_bit_cast(bf16x8, *(const uint4*)&sm[o]);
            al[mf] = __builtin_bit_cast(bf16x8, *(const uint4*)&sm[XPLN + o]);
        }
        #pragma unroll
        for (int mf = 0; mf < 2; ++mf)
            #pragma unroll
            for (int nf = 0; nf < 4; ++nf) {
                acc[mf][nf] = __builtin_amdgcn_mfma_f32_16x16x32_bf16(ah[mf], bh[nf], acc[mf][nf], 0, 0, 0);
                acc[mf][nf] = __builtin_amdgcn_mfma_f32_16x16x32_bf16(ah[mf], bl[nf], acc[mf][nf], 0, 0, 0);
                acc[mf][nf] = __builtin_amdgcn_mfma_f32_16x16x32_bf16(al[mf], bh[nf], acc[mf][nf], 0, 0, 0);
            }
    }

    // -------- bias+relu, split to bf16 hi/lo, transpose to [row][k] LDS ----
    __syncthreads();   // all x reads done; reuse sm for h planes
    {
        float b1v[4];
        #pragma unroll
        for (int nf = 0; nf < 4; ++nf)
            b1v[nf] = b1[sid * HD + w * 64 + nf * 16 + (ln & 15)];
        #pragma unroll
        for (int mf = 0; mf < 2; ++mf)
            #pragma unroll
            for (int nf = 0; nf < 4; ++nf)
                #pragma unroll
                for (int rg = 0; rg < 4; ++rg) {
                    float v = fmaxf(acc[mf][nf][rg] + b1v[nf], 0.f);
                    unsigned short hi = f2bf(v);
                    unsigned short lo = f2bf(v - bf2f(hi));
                    int col = w * 64 + nf * 16 + (ln & 15);        // k of layer2
                    int row = mf * 16 + (ln >> 4) * 4 + rg;        // sample row
                    int o = row * HROWP + col;
                    sm[H_HI + o] = hi;
                    sm[H_LO + o] = lo;
                }
    }
    __syncthreads();

    // -------- layer 2: 8 K-chunks, h from LDS [row][k], W2 frags streamed --
    f32x4 acc2[2][4];
    #pragma unroll
    for (int mf = 0; mf < 2; ++mf)
        #pragma unroll
        for (int nf = 0; nf < 4; ++nf)
            acc2[mf][nf] = (f32x4){0.f, 0.f, 0.f, 0.f};

    #pragma unroll
    for (int kc = 0; kc < NKC2; ++kc) {
        bf16x8 ah[2], al[2], bh[4], bl[4];
        #pragma unroll
        for (int nf = 0; nf < 4; ++nf) {
            int f2 = ((sid * NKC2 + kc) * 16 + (w * 4 + nf)) * 64 + ln;
            bh[nf] = __builtin_bit_cast(bf16x8, w2h[f2]);
            bl[nf] = __builtin_bit_cast(bf16x8, w2l[f2]);
        }
        #pragma unroll
        for (int mf = 0; mf < 2; ++mf) {
            int o = (mf * 16 + (ln & 15)) * HROWP + kc * 32 + (ln >> 4) * 8;
            ah[mf] = __builtin_bit_cast(bf16x8, *(const uint4*)&sm[H_HI + o]);
            al[mf] = __builtin_bit_cast(bf16x8, *(const uint4*)&sm[H_LO + o]);
        }
        #pragma unroll
        for (int mf = 0; mf < 2; ++mf)
            #pragma unroll
            for (int nf = 0; nf < 4; ++nf) {
                acc2[mf][nf] = __builtin_amdgcn_mfma_f32_16x16x32_bf16(ah[mf], bh[nf], acc2[mf][nf], 0, 0, 0);
                acc2[mf][nf] = __builtin_amdgcn_mfma_f32_16x16x32_bf16(ah[mf], bl[nf], acc2[mf][nf], 0, 0, 0);
                acc2[mf][nf] = __builtin_amdgcn_mfma_f32_16x16x32_bf16(al[mf], bh[nf], acc2[mf][nf], 0, 0, 0);
            }
    }

    // -------- layer 3: bias+relu, dot W3, reduce, sigmoid ------------------
    {
        float w3v[4], b2v[4];
        #pragma unroll
        for (int nf = 0; nf < 4; ++nf) {
            int nn = w * 64 + nf * 16 + (ln & 15);
            w3v[nf] = W3[sid * HD + nn];
            b2v[nf] = b2[sid * HD + nn];
        }
        #pragma unroll
        for (int mf = 0; mf < 2; ++mf)
            #pragma unroll
            for (int rg = 0; rg < 4; ++rg) {
                float p = 0.f;
                #pragma unroll
                for (int nf = 0; nf < 4; ++nf)
                    p += fmaxf(acc2[mf][nf][rg] + b2v[nf], 0.f) * w3v[nf];
                p += __shfl_xor(p, 1, 64);
                p += __shfl_xor(p, 2, 64);
                p += __shfl_xor(p, 4, 64);
                p += __shfl_xor(p, 8, 64);
                if ((ln & 15) == 0)
                    hpart[w][mf * 16 + (ln >> 4) * 4 + rg] = p;
            }
    }
    __syncthreads();
    if (tid < MTM) {
        float s = hpart[0][tid] + hpart[1][tid] + hpart[2][tid] + hpart[3][tid] + b3[sid];
        if (tid < nrows)
            out[rid[tid]] = 1.f / (1.f + expf(-s));
    }
}

extern "C" void kernel_launch(void* const* d_in, const int* in_sizes, int n_in,
                              void* d_out, int out_size, void* d_ws, size_t ws_size,
                              hipStream_t stream)
{
    const float* obs = (const float*)d_in[0];
    const float* act = (const float*)d_in[1];
    const int*   sk  = (const int*)d_in[2];
    const float* W1  = (const float*)d_in[3];
    const float* b1  = (const float*)d_in[4];
    const float* W2  = (const float*)d_in[5];
    const float* b2  = (const float*)d_in[6];
    const float* W3  = (const float*)d_in[7];
    const float* b3  = (const float*)d_in[8];
    float* out = (float*)d_out;
    int B = in_sizes[2];
    int* ws = (int*)d_ws;
    unsigned char* wsb = (unsigned char*)d_ws;

    // zero histogram counters
    hipMemsetAsync(ws, 0, 16 * sizeof(int), stream);

    // parallel hist + W conversion in one grid
    int grid1 = NBH + F1 / 256 + F2 / 256;       // 128 + 832 + 512 = 1472
    hipLaunchKernelGGL(sortconv_k, dim3(grid1), dim3(256), 0, stream,
                       sk, ws, B, W1, W2, wsb);
    hipLaunchKernelGGL(prefix_k, dim3(1), dim3(64), 0, stream, ws);
    hipLaunchKernelGGL(scatter_k, dim3(NBH), dim3(256), 0, stream, sk, ws, B);

    int ntiles = B / MTM + NSK - 1;              // 1039 worst case
    hipLaunchKernelGGL(moe_m, dim3(ntiles), dim3(256), 0, stream,
                       obs, act, b1, b2, W3, b3, ws, wsb, out);
}